// Round 2
// baseline (405.490 us; speedup 1.0000x reference)
//
#include <hip/hip_runtime.h>

#define NN 1024
#define CC 768
#define OO 768
#define RR 16
#define MM 8192
#define KK (CC*RR)      /* 12288 */
#define BM 128
#define BO 64
#define BK 64
#define KTILES (KK/BK)  /* 192 */

typedef __bf16 bf16x8 __attribute__((ext_vector_type(8)));
typedef float  f32x4  __attribute__((ext_vector_type(4)));

__device__ static __forceinline__ void gl_lds16(const void* g, void* l) {
    __builtin_amdgcn_global_load_lds(
        (const __attribute__((address_space(1))) void*)g,
        (__attribute__((address_space(3))) void*)l,
        16, 0, 0);
}

// ---- prep: weight fp32 -> bf16 (ws), and bterm[n,o] = coef[n,:]·bias[o,:] ----
__global__ __launch_bounds__(256) void k_prep(const float* __restrict__ w,
                                              const float* __restrict__ coef,
                                              const float* __restrict__ bias,
                                              __bf16* __restrict__ wbf,
                                              float* __restrict__ bterm) {
    long id = blockIdx.x;
    if (id < 4608) {                       // convert 9.44M weights, 8/thread
        long u = (id * 256 + threadIdx.x) * 8;
        float4 a = *(const float4*)(w + u);
        float4 b = *(const float4*)(w + u + 4);
        bf16x8 v = {(__bf16)a.x, (__bf16)a.y, (__bf16)a.z, (__bf16)a.w,
                    (__bf16)b.x, (__bf16)b.y, (__bf16)b.z, (__bf16)b.w};
        *(bf16x8*)(wbf + u) = v;
    } else {                               // bterm: float4-vectorized dot16
        int i = (int)(id - 4608) * 256 + threadIdx.x;
        int n = i / OO, o = i - n * OO;
        const float4* cp = (const float4*)(coef + n * RR);
        const float4* bp = (const float4*)(bias + o * RR);
        float s = 0.f;
#pragma unroll
        for (int q = 0; q < 4; ++q) {
            float4 c4 = cp[q], b4 = bp[q];
            s += c4.x * b4.x + c4.y * b4.y + c4.z * b4.z + c4.w * b4.w;
        }
        bterm[i] = s;
    }
}

// ---- GEMM: 128x64 tiles, 768 blocks (3/CU), A-fragments built in registers ----
// A[m, c*16+r] = x[m,c] * coef[n,r]; lane's A-frag element: k = ks*32+quad*8+j
//  -> c = kt*4 + ks*2 + (quad>>1), r = (quad&1)*8 + j  (one x scalar, 8 coef regs)
__global__ __launch_bounds__(256, 3) void k_gemm(const float* __restrict__ x,
                                                 const float* __restrict__ coef,
                                                 const __bf16* __restrict__ wbf,
                                                 const float* __restrict__ bterm,
                                                 float* __restrict__ out) {
    __shared__ __bf16 lB[2][BO * BK];      // double-buffered B, 8KB each

    const int tid = threadIdx.x;

    // XCD-aware swizzle: 8 mtiles per XCD, all 12 otiles stream through its L2
    int id    = blockIdx.x;                // 0..767
    int xcd   = id & 7;
    int slot  = id >> 3;                   // 0..95
    int otile = slot >> 3;                 // 0..11
    int mtile = xcd * 8 + (slot & 7);      // 0..63
    const int m0 = mtile * BM, o0 = otile * BO;

    const int lane = tid & 63, wave = tid >> 6;
    const int wm = (wave & 1) * 64, wo = (wave >> 1) * 32;  // wave-tile 64x32
    const int lrow = lane & 15, quad = lane >> 4;
    const int qh = quad >> 1, ql = quad & 1;

    // per-lane coef registers + x row pointers (4 m-fragments)
    float cf8[4][8];
    const float* xrow[4];
#pragma unroll
    for (int f = 0; f < 4; ++f) {
        int m = m0 + wm + f * 16 + lrow;
        int n = m & (NN - 1);
#pragma unroll
        for (int j = 0; j < 8; j += 4) {
            float4 t = *(const float4*)(coef + n * RR + ql * 8 + j);
            cf8[f][j] = t.x; cf8[f][j + 1] = t.y; cf8[f][j + 2] = t.z; cf8[f][j + 3] = t.w;
        }
        xrow[f] = x + (long)m * CC;
    }

    // B staging: 512 x 16B DMA per tile, 2 per thread, global-side XOR swizzle
    auto stage = [&](int kt, int buf) {
#pragma unroll
        for (int s = 0; s < 2; ++s) {
            int u = s * 256 + tid;
            int row = u >> 3, cl = u & 7;
            int g = cl ^ (row & 7);
            const __bf16* gp = wbf + (long)(o0 + row) * KK + kt * BK + g * 8;
            gl_lds16(gp, ((char*)&lB[buf][0]) + u * 16);
        }
    };

    f32x4 acc[4][2] = {};

    stage(0, 0);
    float4 x4[4];
#pragma unroll
    for (int f = 0; f < 4; ++f) x4[f] = *(const float4*)(xrow[f]);
    __syncthreads();

#pragma unroll 1
    for (int kt = 0; kt < KTILES; ++kt) {
        const int cur = kt & 1;
        if (kt + 1 < KTILES) stage(kt + 1, cur ^ 1);   // DMA drained by end barrier
        // prefetch next x chunk (uniform branch; clamp to stay in bounds)
        float4 x4n[4];
        const int ktn = (kt + 1 < KTILES) ? kt + 1 : kt;
#pragma unroll
        for (int f = 0; f < 4; ++f) x4n[f] = *(const float4*)(xrow[f] + ktn * 4);

#pragma unroll
        for (int ks = 0; ks < 2; ++ks) {
            bf16x8 bfr[2];
            const int kb = ks * 4 + quad;
#pragma unroll
            for (int io = 0; io < 2; ++io) {
                int row = wo + io * 16 + lrow;
                bfr[io] = *(const bf16x8*)(&lB[cur][row * BK + ((kb ^ (row & 7)) * 8)]);
            }
#pragma unroll
            for (int f = 0; f < 4; ++f) {
                float xs = ks ? (qh ? x4[f].w : x4[f].z)
                              : (qh ? x4[f].y : x4[f].x);
                bf16x8 af;
#pragma unroll
                for (int j = 0; j < 8; ++j) af[j] = (__bf16)(xs * cf8[f][j]);
#pragma unroll
                for (int io = 0; io < 2; ++io)
                    acc[f][io] = __builtin_amdgcn_mfma_f32_16x16x32_bf16(
                        af, bfr[io], acc[f][io], 0, 0, 0);
            }
        }
#pragma unroll
        for (int f = 0; f < 4; ++f) x4[f] = x4n[f];
        __syncthreads();   // reads of lB[cur] done before next iter overwrites it
    }

    // ---- epilogue: D col=lane&15 (o), row=quad*4+reg (m); add bterm ----
#pragma unroll
    for (int f = 0; f < 4; ++f) {
#pragma unroll
        for (int io = 0; io < 2; ++io) {
            int o = o0 + wo + io * 16 + lrow;
#pragma unroll
            for (int r = 0; r < 4; ++r) {
                int moff = wm + f * 16 + quad * 4 + r;
                long m = m0 + moff;
                int n = (int)(m & (NN - 1));
                out[m * OO + o] = acc[f][io][r] + bterm[(long)n * OO + o];
            }
        }
    }
}

// ---- fallback if workspace too small (correctness-only) ----
__global__ void k_naive(const float* __restrict__ x, const float* __restrict__ coef,
                        const float* __restrict__ w, const float* __restrict__ bias,
                        float* __restrict__ out) {
    long i = (long)blockIdx.x * 256 + threadIdx.x;
    if (i >= (long)MM * OO) return;
    int o = (int)(i % OO);
    long m = i / OO;
    int n = (int)(m & (NN - 1));
    float cf[16];
#pragma unroll
    for (int r = 0; r < 16; ++r) cf[r] = coef[n * RR + r];
    const float* xr = x + m * CC;
    const float* wr = w + (long)o * CC * RR;
    float s = 0.f;
    for (int c = 0; c < CC; ++c) {
        float t = 0.f;
#pragma unroll
        for (int r = 0; r < 16; ++r) t += cf[r] * wr[c * RR + r];
        s += xr[c] * t;
    }
    float bs = 0.f;
#pragma unroll
    for (int r = 0; r < 16; ++r) bs += cf[r] * bias[o * RR + r];
    out[i] = s + bs;
}

extern "C" void kernel_launch(void* const* d_in, const int* in_sizes, int n_in,
                              void* d_out, int out_size, void* d_ws, size_t ws_size,
                              hipStream_t stream) {
    const float* x    = (const float*)d_in[0];
    const float* coef = (const float*)d_in[1];
    const float* w    = (const float*)d_in[2];
    const float* bias = (const float*)d_in[3];
    float* out = (float*)d_out;

    const size_t wbf_bytes = (size_t)OO * KK * sizeof(__bf16);   // 18,874,368
    const size_t bt_bytes  = (size_t)NN * OO * sizeof(float);    //  3,145,728

    if (ws_size >= wbf_bytes + bt_bytes) {
        __bf16* wbf  = (__bf16*)d_ws;
        float*  btrm = (float*)((char*)d_ws + wbf_bytes);
        k_prep<<<7680, 256, 0, stream>>>(w, coef, bias, wbf, btrm);
        k_gemm<<<768, 256, 0, stream>>>(x, coef, wbf, btrm, out);
    } else {
        k_naive<<<(int)(((long)MM * OO + 255) / 256), 256, 0, stream>>>(x, coef, w, bias, out);
    }
}

// Round 3
// 285.226 us; speedup vs baseline: 1.4216x; 1.4216x over previous
//
#include <hip/hip_runtime.h>

#define NN 1024
#define CC 768
#define OO 768
#define RR 16
#define MM 8192
#define KK (CC*RR)      /* 12288 */
#define BM 128
#define BO 128
#define BK 64
#define KTILES (KK/BK)  /* 192 */
#define KSPLIT 2
#define KHALF (KTILES/KSPLIT)  /* 96 */

typedef __bf16 bf16x8 __attribute__((ext_vector_type(8)));
typedef float  f32x4  __attribute__((ext_vector_type(4)));

__device__ static __forceinline__ void gl_lds16(const void* g, void* l) {
    __builtin_amdgcn_global_load_lds(
        (const __attribute__((address_space(1))) void*)g,
        (__attribute__((address_space(3))) void*)l,
        16, 0, 0);
}

// ---- prep: weight fp32->bf16, bterm[n,o]=coef[n,:]·bias[o,:], zero out ----
__global__ __launch_bounds__(256) void k_prep(const float* __restrict__ w,
                                              const float* __restrict__ coef,
                                              const float* __restrict__ bias,
                                              __bf16* __restrict__ wbf,
                                              float* __restrict__ bterm,
                                              float* __restrict__ outz) {
    long id = blockIdx.x;
    if (id < 4608) {                       // convert 9.44M weights, 8/thread
        long u = (id * 256 + threadIdx.x) * 8;
        float4 a = *(const float4*)(w + u);
        float4 b = *(const float4*)(w + u + 4);
        bf16x8 v = {(__bf16)a.x, (__bf16)a.y, (__bf16)a.z, (__bf16)a.w,
                    (__bf16)b.x, (__bf16)b.y, (__bf16)b.z, (__bf16)b.w};
        *(bf16x8*)(wbf + u) = v;
    } else if (id < 7680) {                // bterm: float4-vectorized dot16
        int i = (int)(id - 4608) * 256 + threadIdx.x;
        int n = i / OO, o = i - n * OO;
        const float4* cp = (const float4*)(coef + n * RR);
        const float4* bp = (const float4*)(bias + o * RR);
        float s = 0.f;
#pragma unroll
        for (int q = 0; q < 4; ++q) {
            float4 c4 = cp[q], b4 = bp[q];
            s += c4.x * b4.x + c4.y * b4.y + c4.z * b4.z + c4.w * b4.w;
        }
        bterm[i] = s;
    } else {                               // zero d_out (6.29M floats), 8/thread
        long u = ((id - 7680) * 256 + threadIdx.x) * 8;
        float4 z = {0.f, 0.f, 0.f, 0.f};
        *(float4*)(outz + u) = z;
        *(float4*)(outz + u + 4) = z;
    }
}

// ---- GEMM: 128x128 tile, split-K=2 -> 768 blocks (3/CU even), LDS A-build ----
__global__ __launch_bounds__(256, 3) void k_gemm(const float* __restrict__ x,
                                                 const float* __restrict__ coef,
                                                 const __bf16* __restrict__ wbf,
                                                 const float* __restrict__ bterm,
                                                 float* __restrict__ out) {
    __shared__ __bf16 lA[BM * BK];
    __shared__ __bf16 lB[BO * BK];

    const int tid = threadIdx.x;

    // id -> (xcd, kh, otile, mtile); same-XCD blocks share W col-tiles for L2
    int id    = blockIdx.x;          // 0..767
    int xcd   = id & 7;
    int slot  = id >> 3;             // 0..95
    int kh    = slot & 1;
    int slot2 = slot >> 1;           // 0..47
    int otile = slot2 >> 3;          // 0..5
    int mtile = xcd * 8 + (slot2 & 7);
    const int m0 = mtile * BM, o0 = otile * BO;
    const int kt0 = kh * KHALF, kt1 = kt0 + KHALF;

    // ---- A-build mapping: thread -> (row m, c-pair) ----
    const int am     = tid & 127;
    const int ahalf  = tid >> 7;
    const int m_glob = m0 + am;
    const int n_idx  = m_glob & (NN - 1);
    const float* xrow = x + (long)m_glob * CC;

    float cf[16];
#pragma unroll
    for (int r = 0; r < 16; r += 4) {
        float4 t4 = *(const float4*)(coef + n_idx * RR + r);
        cf[r] = t4.x; cf[r + 1] = t4.y; cf[r + 2] = t4.z; cf[r + 3] = t4.w;
    }

    const int lane = tid & 63, wave = tid >> 6;
    const int wm = (wave & 1) * 64, wo = (wave >> 1) * 64;
    const int lrow = lane & 15, quad = lane >> 4;

    f32x4 acc[4][4] = {};

    float2 x2 = *(const float2*)(xrow + kt0 * 4 + 2 * ahalf);

#pragma unroll 1
    for (int kt = kt0; kt < kt1; ++kt) {
        // --- stage B (async DMA, global-side XOR swizzle) ---
#pragma unroll
        for (int s = 0; s < 4; ++s) {
            int u = s * 256 + tid;
            int row = u >> 3, cl = u & 7;
            int g = cl ^ (row & 7);
            const __bf16* gp = wbf + (long)(o0 + row) * KK + kt * BK + g * 8;
            gl_lds16(gp, ((char*)lB) + u * 16);
        }
        // --- prefetch next x chunk ---
        float2 x2n = x2;
        if (kt + 1 < kt1) x2n = *(const float2*)(xrow + (kt + 1) * 4 + 2 * ahalf);
        // --- build A tile: 2 c's x 16 r's -> 4 swizzled 16B chunks ---
#pragma unroll
        for (int ci = 0; ci < 2; ++ci) {
            float xv = (ci == 0) ? x2.x : x2.y;
            int c_local = 2 * ahalf + ci;
#pragma unroll
            for (int rh = 0; rh < 2; ++rh) {
                bf16x8 v;
#pragma unroll
                for (int j = 0; j < 8; ++j) v[j] = (__bf16)(xv * cf[rh * 8 + j]);
                int kb  = c_local * 2 + rh;
                int kbs = kb ^ (am & 7);
                *(bf16x8*)(&lA[am * BK + kbs * 8]) = v;
            }
        }
        x2 = x2n;
        __syncthreads();   // drains B-DMA (vmcnt) + A ds_writes (lgkmcnt)

        // --- compute: 2 k-steps x 16 MFMA ---
#pragma unroll
        for (int ks = 0; ks < 2; ++ks) {
            bf16x8 af[4], bfr[4];
            int kb = ks * 4 + quad;
#pragma unroll
            for (int im = 0; im < 4; ++im) {
                int row = wm + im * 16 + lrow;
                af[im] = *(const bf16x8*)(&lA[row * BK + (kb ^ (row & 7)) * 8]);
            }
#pragma unroll
            for (int io = 0; io < 4; ++io) {
                int row = wo + io * 16 + lrow;
                bfr[io] = *(const bf16x8*)(&lB[row * BK + (kb ^ (row & 7)) * 8]);
            }
#pragma unroll
            for (int im = 0; im < 4; ++im)
#pragma unroll
                for (int io = 0; io < 4; ++io)
                    acc[im][io] = __builtin_amdgcn_mfma_f32_16x16x32_bf16(
                        af[im], bfr[io], acc[im][io], 0, 0, 0);
        }
        __syncthreads();
    }

    // ---- epilogue: atomic accumulate; kh==0 also adds bterm ----
#pragma unroll
    for (int im = 0; im < 4; ++im) {
#pragma unroll
        for (int io = 0; io < 4; ++io) {
            int o = o0 + wo + io * 16 + lrow;
#pragma unroll
            for (int r = 0; r < 4; ++r) {
                int moff = wm + im * 16 + quad * 4 + r;
                long m = m0 + moff;
                int n = (int)(m & (NN - 1));
                float v = acc[im][io][r];
                if (kh == 0) v += bterm[(long)n * OO + o];
                atomicAdd(&out[m * OO + o], v);
            }
        }
    }
}

// ---- fallback if workspace too small (correctness-only) ----
__global__ void k_naive(const float* __restrict__ x, const float* __restrict__ coef,
                        const float* __restrict__ w, const float* __restrict__ bias,
                        float* __restrict__ out) {
    long i = (long)blockIdx.x * 256 + threadIdx.x;
    if (i >= (long)MM * OO) return;
    int o = (int)(i % OO);
    long m = i / OO;
    int n = (int)(m & (NN - 1));
    float cf[16];
#pragma unroll
    for (int r = 0; r < 16; ++r) cf[r] = coef[n * RR + r];
    const float* xr = x + m * CC;
    const float* wr = w + (long)o * CC * RR;
    float s = 0.f;
    for (int c = 0; c < CC; ++c) {
        float t = 0.f;
#pragma unroll
        for (int r = 0; r < 16; ++r) t += cf[r] * wr[c * RR + r];
        s += xr[c] * t;
    }
    float bs = 0.f;
#pragma unroll
    for (int r = 0; r < 16; ++r) bs += cf[r] * bias[o * RR + r];
    out[i] = s + bs;
}

extern "C" void kernel_launch(void* const* d_in, const int* in_sizes, int n_in,
                              void* d_out, int out_size, void* d_ws, size_t ws_size,
                              hipStream_t stream) {
    const float* x    = (const float*)d_in[0];
    const float* coef = (const float*)d_in[1];
    const float* w    = (const float*)d_in[2];
    const float* bias = (const float*)d_in[3];
    float* out = (float*)d_out;

    const size_t wbf_bytes = (size_t)OO * KK * sizeof(__bf16);   // 18,874,368
    const size_t bt_bytes  = (size_t)NN * OO * sizeof(float);    //  3,145,728

    if (ws_size >= wbf_bytes + bt_bytes) {
        __bf16* wbf  = (__bf16*)d_ws;
        float*  btrm = (float*)((char*)d_ws + wbf_bytes);
        // 4608 convert + 3072 bterm + 3072 zero-out = 10752 blocks
        k_prep<<<10752, 256, 0, stream>>>(w, coef, bias, wbf, btrm, out);
        k_gemm<<<768, 256, 0, stream>>>(x, coef, wbf, btrm, out);
    } else {
        k_naive<<<(int)(((long)MM * OO + 255) / 256), 256, 0, stream>>>(x, coef, w, bias, out);
    }
}